// Round 1
// baseline (147.320 us; speedup 1.0000x reference)
//
#include <hip/hip_runtime.h>

// Batched Kalman filter: out = C @ (x_pred + P_pred H^T S^-1 (z - H x_pred))
// P_new is never needed (output only depends on x_new). No explicit inverse:
// solve S w = y (8x8 SPD, GE without pivoting), x_new = x_pred + V w.
//
// Layout: 8 threads per batch element (thread i owns rows i and i+8 of all
// 16-row matrices), 32 elements per 256-thread block. Cross-thread matmul
// (P_pred = phi * U) goes through LDS with 260-float element stride
// (conflict-free b128 broadcast reads). 8x8 solve = lane-parallel GE via
// __shfl(width=8).

#define QFMA(ACC, OFF, A, V) { ACC[(OFF)+0] += (A)*(V).x; ACC[(OFF)+1] += (A)*(V).y; ACC[(OFF)+2] += (A)*(V).z; ACC[(OFF)+3] += (A)*(V).w; }

__global__ __launch_bounds__(256) void kalman_fused(
    const float* __restrict__ z,
    const float* __restrict__ x0,
    const float* __restrict__ P0,
    const float* __restrict__ phi,
    const float* __restrict__ Hm,
    const float* __restrict__ Cm,
    const float* __restrict__ Qd,
    const float* __restrict__ Rd,
    float* __restrict__ out,
    int bs)
{
    __shared__ __align__(16) float phiT[256];   // [k*16+l] = phi[l][k]
    __shared__ __align__(16) float phiN[256];   // row-major phi
    __shared__ __align__(16) float HT[128];     // [k*8+m] = H[m][k]
    __shared__ __align__(16) float Hn[128];     // row-major H
    __shared__ __align__(16) float Cs[128];     // row-major C
    __shared__ __align__(16) float Ub[32*260];  // per-element U (16x16) then V (16x8)
    __shared__ __align__(16) float x0s[32*20];
    __shared__ __align__(16) float xps[32*20];
    __shared__ __align__(16) float xns[32*20];

    const int tid = threadIdx.x;
    const int e = tid >> 3;      // element within block (0..31)
    const int i = tid & 7;       // lane within element (0..7)
    long b = (long)blockIdx.x * 32 + e;
    const bool valid = (b < (long)bs);
    if (!valid) b = (long)bs - 1;

    // ---- stage constants ----
    {
        const int r = tid >> 4, c = tid & 15;
        const float v = phi[r * 16 + c];
        phiN[r * 16 + c] = v;
        phiT[c * 16 + r] = v;
        if (tid < 128) {
            const int m = tid >> 4, k = tid & 15;
            const float h = Hm[m * 16 + k];
            Hn[m * 16 + k] = h;
            HT[k * 8 + m] = h;
            Cs[tid] = Cm[tid];
        }
    }
    // ---- stage x0 ----
    x0s[e * 20 + i]     = x0[b * 16 + i];
    x0s[e * 20 + i + 8] = x0[b * 16 + i + 8];

    // ---- load P0 rows i, i+8 ----
    float p0r[16], p1r[16];
    {
        const float4* P0v = reinterpret_cast<const float4*>(P0 + (size_t)b * 256);
#pragma unroll
        for (int q = 0; q < 4; ++q) {
            const float4 A = P0v[i * 4 + q];
            const float4 B = P0v[(i + 8) * 4 + q];
            p0r[4*q+0] = A.x; p0r[4*q+1] = A.y; p0r[4*q+2] = A.z; p0r[4*q+3] = A.w;
            p1r[4*q+0] = B.x; p1r[4*q+1] = B.y; p1r[4*q+2] = B.z; p1r[4*q+3] = B.w;
        }
    }

    __syncthreads();  // constants + x0 staged

    // ---- U = P0 * phi^T : u[r][l] = sum_k P0[r][k] * phi[l][k] ----
    float u0[16], u1[16];
#pragma unroll
    for (int l = 0; l < 16; ++l) { u0[l] = 0.f; u1[l] = 0.f; }
#pragma unroll
    for (int k = 0; k < 16; ++k) {
        const float4 c0 = *reinterpret_cast<const float4*>(&phiT[k * 16 + 0]);
        const float4 c1 = *reinterpret_cast<const float4*>(&phiT[k * 16 + 4]);
        const float4 c2 = *reinterpret_cast<const float4*>(&phiT[k * 16 + 8]);
        const float4 c3 = *reinterpret_cast<const float4*>(&phiT[k * 16 + 12]);
        const float a0 = p0r[k], a1 = p1r[k];
        QFMA(u0, 0, a0, c0) QFMA(u0, 4, a0, c1) QFMA(u0, 8, a0, c2) QFMA(u0, 12, a0, c3)
        QFMA(u1, 0, a1, c0) QFMA(u1, 4, a1, c1) QFMA(u1, 8, a1, c2) QFMA(u1, 12, a1, c3)
    }

    // ---- phi rows i, i+8 into registers ----
    float ph0[16], ph1[16];
#pragma unroll
    for (int q = 0; q < 4; ++q) {
        const float4 A = *reinterpret_cast<const float4*>(&phiN[i * 16 + 4 * q]);
        const float4 B = *reinterpret_cast<const float4*>(&phiN[(i + 8) * 16 + 4 * q]);
        ph0[4*q+0] = A.x; ph0[4*q+1] = A.y; ph0[4*q+2] = A.z; ph0[4*q+3] = A.w;
        ph1[4*q+0] = B.x; ph1[4*q+1] = B.y; ph1[4*q+2] = B.z; ph1[4*q+3] = B.w;
    }

    // ---- x_pred rows: xp[r] = sum_j phi[r][j] * x0[j] ----
    float xp0 = 0.f, xp1 = 0.f;
#pragma unroll
    for (int q = 0; q < 4; ++q) {
        const float4 X = *reinterpret_cast<const float4*>(&x0s[e * 20 + 4 * q]);
        xp0 += ph0[4*q+0]*X.x + ph0[4*q+1]*X.y + ph0[4*q+2]*X.z + ph0[4*q+3]*X.w;
        xp1 += ph1[4*q+0]*X.x + ph1[4*q+1]*X.y + ph1[4*q+2]*X.z + ph1[4*q+3]*X.w;
    }

    // ---- stage U rows and x_pred ----
#pragma unroll
    for (int q = 0; q < 4; ++q) {
        *reinterpret_cast<float4*>(&Ub[e * 260 + i * 16 + 4 * q]) =
            make_float4(u0[4*q+0], u0[4*q+1], u0[4*q+2], u0[4*q+3]);
        *reinterpret_cast<float4*>(&Ub[e * 260 + (i + 8) * 16 + 4 * q]) =
            make_float4(u1[4*q+0], u1[4*q+1], u1[4*q+2], u1[4*q+3]);
    }
    xps[e * 20 + i]     = xp0;
    xps[e * 20 + i + 8] = xp1;
    __syncthreads();  // U, x_pred staged

    // ---- P_pred = phi * U (+ diag Q) ----
    float pp0[16], pp1[16];
#pragma unroll
    for (int l = 0; l < 16; ++l) { pp0[l] = 0.f; pp1[l] = 0.f; }
#pragma unroll
    for (int j = 0; j < 16; ++j) {
        const float4 c0 = *reinterpret_cast<const float4*>(&Ub[e * 260 + j * 16 + 0]);
        const float4 c1 = *reinterpret_cast<const float4*>(&Ub[e * 260 + j * 16 + 4]);
        const float4 c2 = *reinterpret_cast<const float4*>(&Ub[e * 260 + j * 16 + 8]);
        const float4 c3 = *reinterpret_cast<const float4*>(&Ub[e * 260 + j * 16 + 12]);
        const float a0 = ph0[j], a1 = ph1[j];
        QFMA(pp0, 0, a0, c0) QFMA(pp0, 4, a0, c1) QFMA(pp0, 8, a0, c2) QFMA(pp0, 12, a0, c3)
        QFMA(pp1, 0, a1, c0) QFMA(pp1, 4, a1, c1) QFMA(pp1, 8, a1, c2) QFMA(pp1, 12, a1, c3)
    }
    {
        const float qa = Qd[i], qb = Qd[i + 8];
#pragma unroll
        for (int l = 0; l < 16; ++l) {
            pp0[l] += (l == i)     ? qa : 0.f;
            pp1[l] += (l == i + 8) ? qb : 0.f;
        }
    }
    __syncthreads();  // all U reads done; safe to overwrite Ub with V

    // ---- V = P_pred * H^T : v[r][m] = sum_k pp[r][k] * H[m][k] ----
    float v0[8], v1[8];
#pragma unroll
    for (int m = 0; m < 8; ++m) { v0[m] = 0.f; v1[m] = 0.f; }
#pragma unroll
    for (int k = 0; k < 16; ++k) {
        const float4 h0 = *reinterpret_cast<const float4*>(&HT[k * 8 + 0]);
        const float4 h1 = *reinterpret_cast<const float4*>(&HT[k * 8 + 4]);
        const float a0 = pp0[k], a1 = pp1[k];
        QFMA(v0, 0, a0, h0) QFMA(v0, 4, a0, h1)
        QFMA(v1, 0, a1, h0) QFMA(v1, 4, a1, h1)
    }
    *reinterpret_cast<float4*>(&Ub[e * 260 + i * 8 + 0]) = make_float4(v0[0], v0[1], v0[2], v0[3]);
    *reinterpret_cast<float4*>(&Ub[e * 260 + i * 8 + 4]) = make_float4(v0[4], v0[5], v0[6], v0[7]);
    *reinterpret_cast<float4*>(&Ub[e * 260 + (i + 8) * 8 + 0]) = make_float4(v1[0], v1[1], v1[2], v1[3]);
    *reinterpret_cast<float4*>(&Ub[e * 260 + (i + 8) * 8 + 4]) = make_float4(v1[4], v1[5], v1[6], v1[7]);
    __syncthreads();  // V staged

    // ---- S row i = H[i,:] * V (+R), y_i ----
    float hrow[16];
#pragma unroll
    for (int q = 0; q < 4; ++q) {
        const float4 A = *reinterpret_cast<const float4*>(&Hn[i * 16 + 4 * q]);
        hrow[4*q+0] = A.x; hrow[4*q+1] = A.y; hrow[4*q+2] = A.z; hrow[4*q+3] = A.w;
    }
    float s[8];
#pragma unroll
    for (int m = 0; m < 8; ++m) s[m] = 0.f;
#pragma unroll
    for (int j = 0; j < 16; ++j) {
        const float4 a = *reinterpret_cast<const float4*>(&Ub[e * 260 + j * 8 + 0]);
        const float4 c = *reinterpret_cast<const float4*>(&Ub[e * 260 + j * 8 + 4]);
        const float hij = hrow[j];
        QFMA(s, 0, hij, a) QFMA(s, 4, hij, c)
    }
    {
        const float Ri = Rd[i];
#pragma unroll
        for (int m = 0; m < 8; ++m) s[m] += (m == i) ? Ri : 0.f;
    }

    float yv = z[b * 8 + i];
#pragma unroll
    for (int q = 0; q < 4; ++q) {
        const float4 X = *reinterpret_cast<const float4*>(&xps[e * 20 + 4 * q]);
        yv -= hrow[4*q+0]*X.x + hrow[4*q+1]*X.y + hrow[4*q+2]*X.z + hrow[4*q+3]*X.w;
    }

    // ---- solve S w = y : lane-parallel GE (no pivoting; S is SPD) ----
#pragma unroll
    for (int k = 0; k < 7; ++k) {
        float pr[8];
#pragma unroll
        for (int j = 0; j < 8; ++j) pr[j] = __shfl(s[j], k, 8);
        const float py = __shfl(yv, k, 8);
        if (i > k) {
            const float f = s[k] / pr[k];
#pragma unroll
            for (int j = 0; j < 8; ++j) s[j] -= f * pr[j];
            yv -= f * py;
        }
    }
    float w[8];
#pragma unroll
    for (int k = 7; k >= 0; --k) {
        const float num = __shfl(yv, k, 8);
        const float den = __shfl(s[k], k, 8);
        const float wk = num / den;
        w[k] = wk;
        if (i < k) yv -= s[k] * wk;
    }

    // ---- x_new rows, stage ----
    float xn0 = xp0, xn1 = xp1;
#pragma unroll
    for (int m = 0; m < 8; ++m) { xn0 += v0[m] * w[m]; xn1 += v1[m] * w[m]; }
    xns[e * 20 + i]     = xn0;
    xns[e * 20 + i + 8] = xn1;
    __syncthreads();  // x_new staged

    // ---- out[b][i] = C[i,:] . x_new ----
    float o = 0.f;
#pragma unroll
    for (int q = 0; q < 4; ++q) {
        const float4 A = *reinterpret_cast<const float4*>(&Cs[i * 16 + 4 * q]);
        const float4 X = *reinterpret_cast<const float4*>(&xns[e * 20 + 4 * q]);
        o += A.x * X.x + A.y * X.y + A.z * X.z + A.w * X.w;
    }
    if (valid) out[b * 8 + i] = o;
}

extern "C" void kernel_launch(void* const* d_in, const int* in_sizes, int n_in,
                              void* d_out, int out_size, void* d_ws, size_t ws_size,
                              hipStream_t stream)
{
    const float* z   = (const float*)d_in[0];
    const float* x0  = (const float*)d_in[1];
    const float* P0  = (const float*)d_in[2];
    const float* phi = (const float*)d_in[3];
    const float* H   = (const float*)d_in[4];
    const float* C   = (const float*)d_in[5];
    const float* Qd  = (const float*)d_in[6];
    const float* Rd  = (const float*)d_in[7];
    float* out = (float*)d_out;

    const int bs = in_sizes[0] / 8;          // z is [bs, 8]
    const int blocks = (bs + 31) / 32;       // 32 elements per block
    hipLaunchKernelGGL(kalman_fused, dim3(blocks), dim3(256), 0, stream,
                       z, x0, P0, phi, H, C, Qd, Rd, out, bs);
}